// Round 2
// baseline (589.952 us; speedup 1.0000x reference)
//
#include <hip/hip_runtime.h>

// PlasticSynapse elementwise update:
//   new_w = clip(baseline*ALPHA + w*(1-ALPHA)
//                + R[b] * |kappa[o,i]| * (post[b,o]*pre[b,i] + SIGMA*noise),
//                0, 1)
// Shapes: w,noise,out: (B,OUT,IN); baseline,kappa: (OUT,IN); pre: (B,IN);
//         post: (B,OUT); R: (B,1,1).  B=64, OUT=1024, IN=1024, all fp32.
//
// Structure: flat one-shot waves (round-0 winner), but 2 float4 per thread
// paired at half-tensor offset (b and b+32, same o,i4):
//   - 6 big vector loads issued per thread before any wait (2x MLP vs round 0)
//   - baseline/kappa loaded ONCE, shared by both elements
//   - no loop-carried dependence, wave churn keeps load queues full
// Round-1 lesson: grid-stride loop at VGPR=24 serialized loads -> regressed.

constexpr int B_DIM  = 64;
constexpr int OUT_D  = 1024;
constexpr int IN_D   = 1024;
constexpr int IN4    = IN_D / 4;              // 256 float4 per row
constexpr int TOTAL4 = B_DIM * OUT_D * IN4;   // 16,777,216 float4
constexpr int HALF4  = TOTAL4 / 2;            // 8,388,608
constexpr int BLOCK  = 256;

constexpr float ALPHA  = 0.01f;               // DT_W / TAU_W
constexpr float ONE_MA = 1.0f - ALPHA;        // 0.99
constexpr float SIGMA  = 0.14142135623730951f; // sqrt(2/ALPHA)*0.01

__global__ __launch_bounds__(BLOCK)
void PlasticSynapse_69466801045994_kernel(
    const float4* __restrict__ w,
    const float4* __restrict__ baseline,
    const float*  __restrict__ R,
    const float4* __restrict__ pre,
    const float*  __restrict__ post,
    const float4* __restrict__ kappa,
    const float4* __restrict__ noise,
    float4*       __restrict__ out)
{
    // Exactly HALF4 threads; each handles idx and idx + HALF4.
    const int idx = blockIdx.x * BLOCK + threadIdx.x;

    // Decode (b, o, i4). Second element differs only in b (+32):
    // HALF4 = 2^23 -> adds 32 to b, leaves o and i4 untouched.
    const int i4 = idx & (IN4 - 1);
    const int bo = idx >> 8;
    const int o  = bo & (OUT_D - 1);
    const int b  = bo >> 10;                  // 0..31
    const int b2 = b + 32;                    // 32..63
    const int idx2 = idx + HALF4;
    const int oi = o * IN4 + i4;

    // Issue all loads up front: 6 dwordx4 + 6 small, no dependent waits between.
    const float4 wv1 = w[idx];
    const float4 wv2 = w[idx2];
    const float4 nv1 = noise[idx];
    const float4 nv2 = noise[idx2];
    const float4 bl  = baseline[oi];          // shared by both elements
    const float4 kp  = kappa[oi];             // shared by both elements
    const float4 pr1 = pre[b  * IN4 + i4];
    const float4 pr2 = pre[b2 * IN4 + i4];
    const float  po1 = post[b  * OUT_D + o];
    const float  po2 = post[b2 * OUT_D + o];
    const float  r1  = R[b];
    const float  r2  = R[b2];

    const float akx = fabsf(kp.x), aky = fabsf(kp.y);
    const float akz = fabsf(kp.z), akw = fabsf(kp.w);
    const float blx = bl.x * ALPHA, bly = bl.y * ALPHA;
    const float blz = bl.z * ALPHA, blw = bl.w * ALPHA;

    float4 res1, res2;
    res1.x = fminf(fmaxf(fmaf(r1 * akx, fmaf(SIGMA, nv1.x, po1 * pr1.x),
                              fmaf(wv1.x, ONE_MA, blx)), 0.0f), 1.0f);
    res1.y = fminf(fmaxf(fmaf(r1 * aky, fmaf(SIGMA, nv1.y, po1 * pr1.y),
                              fmaf(wv1.y, ONE_MA, bly)), 0.0f), 1.0f);
    res1.z = fminf(fmaxf(fmaf(r1 * akz, fmaf(SIGMA, nv1.z, po1 * pr1.z),
                              fmaf(wv1.z, ONE_MA, blz)), 0.0f), 1.0f);
    res1.w = fminf(fmaxf(fmaf(r1 * akw, fmaf(SIGMA, nv1.w, po1 * pr1.w),
                              fmaf(wv1.w, ONE_MA, blw)), 0.0f), 1.0f);

    res2.x = fminf(fmaxf(fmaf(r2 * akx, fmaf(SIGMA, nv2.x, po2 * pr2.x),
                              fmaf(wv2.x, ONE_MA, blx)), 0.0f), 1.0f);
    res2.y = fminf(fmaxf(fmaf(r2 * aky, fmaf(SIGMA, nv2.y, po2 * pr2.y),
                              fmaf(wv2.y, ONE_MA, bly)), 0.0f), 1.0f);
    res2.z = fminf(fmaxf(fmaf(r2 * akz, fmaf(SIGMA, nv2.z, po2 * pr2.z),
                              fmaf(wv2.z, ONE_MA, blz)), 0.0f), 1.0f);
    res2.w = fminf(fmaxf(fmaf(r2 * akw, fmaf(SIGMA, nv2.w, po2 * pr2.w),
                              fmaf(wv2.w, ONE_MA, blw)), 0.0f), 1.0f);

    out[idx]  = res1;
    out[idx2] = res2;
}

extern "C" void kernel_launch(void* const* d_in, const int* in_sizes, int n_in,
                              void* d_out, int out_size, void* d_ws, size_t ws_size,
                              hipStream_t stream) {
    // setup_inputs() dict order: w, baseline, R, pre, post, kappa, noise
    const float4* w        = (const float4*)d_in[0];
    const float4* baseline = (const float4*)d_in[1];
    const float*  R        = (const float*) d_in[2];
    const float4* pre      = (const float4*)d_in[3];
    const float*  post     = (const float*) d_in[4];
    const float4* kappa    = (const float4*)d_in[5];
    const float4* noise    = (const float4*)d_in[6];
    float4*       out      = (float4*)d_out;

    const int grid = HALF4 / BLOCK;           // 32,768 blocks
    PlasticSynapse_69466801045994_kernel<<<grid, BLOCK, 0, stream>>>(
        w, baseline, R, pre, post, kappa, noise, out);
}